// Round 13
// baseline (208.440 us; speedup 1.0000x reference)
//
#include <hip/hip_runtime.h>

#define NN 50000     // nodes
#define NE 600000    // directed edges (self loops handled separately)
#define NG 64        // graphs
#define DIM 128      // feature dim (D == H == 128)
#define NCLS 10
#define SB 196       // ceil(NN/256)
#define NNP 50176    // SB*256 = 224*224 (padded K for pool GEMM)
#define KBLK 224     // split-K blocks for pool GEMM
#define KCH 224      // K-chunk per block (KBLK*KCH == NNP)
#define CAP 64       // ELL row capacity (multinomial max deg ~33; 64 is safe)
#define E4B ((NE / 4 + 255) / 256)   // edge blocks, 4 edges/thread

typedef unsigned short ushort;
typedef unsigned char uchar;
typedef __attribute__((ext_vector_type(8))) short short8;   // 8 bf16 (4 VGPRs)
typedef __attribute__((ext_vector_type(4))) float float4v;  // 4 fp32 acc
typedef __attribute__((ext_vector_type(2))) float float2v;

__device__ __forceinline__ ushort f2bf(float f) {
    unsigned u = __float_as_uint(f);
    u += 0x7fff + ((u >> 16) & 1);          // RNE
    return (ushort)(u >> 16);
}
// fp8 e4m3 (OCP) encode via HW cvt (RNE, satfinite)
__device__ __forceinline__ uchar f2fp8(float f) {
    int p = __builtin_amdgcn_cvt_pk_fp8_f32(f, f, 0, false);
    return (uchar)(p & 0xff);
}
// decode 16 fp8 (uint4) -> accumulate into a[0..15]
__device__ __forceinline__ void accfp8x16(float* a, uint4 v) {
    float2v p0 = __builtin_amdgcn_cvt_pk_f32_fp8(v.x, false);
    float2v p1 = __builtin_amdgcn_cvt_pk_f32_fp8(v.x, true);
    float2v p2 = __builtin_amdgcn_cvt_pk_f32_fp8(v.y, false);
    float2v p3 = __builtin_amdgcn_cvt_pk_f32_fp8(v.y, true);
    float2v p4 = __builtin_amdgcn_cvt_pk_f32_fp8(v.z, false);
    float2v p5 = __builtin_amdgcn_cvt_pk_f32_fp8(v.z, true);
    float2v p6 = __builtin_amdgcn_cvt_pk_f32_fp8(v.w, false);
    float2v p7 = __builtin_amdgcn_cvt_pk_f32_fp8(v.w, true);
    a[0]  += p0[0]; a[1]  += p0[1]; a[2]  += p1[0]; a[3]  += p1[1];
    a[4]  += p2[0]; a[5]  += p2[1]; a[6]  += p3[0]; a[7]  += p3[1];
    a[8]  += p4[0]; a[9]  += p4[1]; a[10] += p5[0]; a[11] += p5[1];
    a[12] += p6[0]; a[13] += p6[1]; a[14] += p7[0]; a[15] += p7[1];
}

// ---- init: zero cnt + W1 frag prep + zero T + zero dinv tail --------------
__global__ void k_init(int* __restrict__ cnt, const float* __restrict__ W1,
                       ushort* __restrict__ Wsw, float* __restrict__ T,
                       float* __restrict__ dinv) {
    int b = blockIdx.x, t = threadIdx.x;
    if (b < SB) {
        int i = b * 256 + t;
        if (i < NN) cnt[i] = 0;
    } else if (b < SB + 64) {
        int tid = (b - SB) * 256 + t;     // 16384 entries
        int j = tid & 7;
        int lane = (tid >> 3) & 63;
        int frag = tid >> 9;              // nt*4+kc
        int nt = frag >> 2, kc = frag & 3;
        int k = kc * 32 + (lane >> 4) * 8 + j;
        int n = nt * 16 + (lane & 15);
        Wsw[tid] = f2bf(W1[k * DIM + n]);
    } else if (b < SB + 64 + 784) {
        // zero T: 64*NNP floats = 802816 float4 = 784 blocks * 256 thr * 4
        float4* w4 = (float4*)T;
        int base = (b - SB - 64) * 256 + t;
#pragma unroll
        for (int i = 0; i < 4; ++i)
            w4[base + i * 200704] = make_float4(0.f, 0.f, 0.f, 0.f);
    } else {
        if (t < NNP - NN) dinv[NN + t] = 0.f;   // pad tail (pool_gemm reads it)
    }
}

// ------- single-pass ELL fill by dst (4 edges/thread); cnt ends as degree --
__global__ void k_fill(const int* __restrict__ row, const int* __restrict__ col,
                       int* __restrict__ cnt, int* __restrict__ ell) {
    int e = (blockIdx.x * blockDim.x + threadIdx.x) * 4;
    if (e < NE) {
        int4 r = *(const int4*)(row + e);
        int4 c = *(const int4*)(col + e);
        int p0 = atomicAdd(&cnt[c.x], 1);
        if (p0 < CAP) ell[c.x * CAP + p0] = r.x;
        int p1 = atomicAdd(&cnt[c.y], 1);
        if (p1 < CAP) ell[c.y * CAP + p1] = r.y;
        int p2 = atomicAdd(&cnt[c.z], 1);
        if (p2 < CAP) ell[c.z * CAP + p2] = r.z;
        int p3 = atomicAdd(&cnt[c.w], 1);
        if (p3 < CAP) ell[c.w * CAP + p3] = r.w;
    }
}

// ---------------- MFMA GEMM: Hs[n,c] = fp8(dinv[n] * sum_k x[n,k] W1[k,c]) -
// Also materializes dinv[n] = rsqrt(1+deg[n]) for pool_gemm reuse.
__global__ __launch_bounds__(256) void k_gemm_mfma(const float* __restrict__ Ain,
                                                   const ushort* __restrict__ Wsw,
                                                   const int* __restrict__ cnt,
                                                   uchar* __restrict__ Hs,
                                                   float* __restrict__ dinv) {
    const int t = threadIdx.x;
    const int wave = t >> 6, lane = t & 63;
    const int m = lane & 15, quad = lane >> 4;
    const int row0 = blockIdx.x * 64 + wave * 16;

    short8 bfrag[8][4];
#pragma unroll
    for (int nt = 0; nt < 8; ++nt)
#pragma unroll
        for (int kc = 0; kc < 4; ++kc)
            bfrag[nt][kc] = *(const short8*)(Wsw + ((nt * 4 + kc) * 64 + lane) * 8);

    float4v acc[8];
#pragma unroll
    for (int nt = 0; nt < 8; ++nt) acc[nt] = (float4v){0.f, 0.f, 0.f, 0.f};

    const int row = row0 + m;
    const int rclamp = row < NN ? row : NN - 1;

#pragma unroll
    for (int kc = 0; kc < 4; ++kc) {
        const float* ap = Ain + (size_t)rclamp * DIM + kc * 32 + quad * 8;
        float4 v0 = *(const float4*)ap;
        float4 v1 = *(const float4*)(ap + 4);
        union { short8 v; ushort u[8]; } tmp;
        tmp.u[0] = f2bf(v0.x); tmp.u[1] = f2bf(v0.y);
        tmp.u[2] = f2bf(v0.z); tmp.u[3] = f2bf(v0.w);
        tmp.u[4] = f2bf(v1.x); tmp.u[5] = f2bf(v1.y);
        tmp.u[6] = f2bf(v1.z); tmp.u[7] = f2bf(v1.w);
        short8 a = tmp.v;
#pragma unroll
        for (int nt = 0; nt < 8; ++nt)
            acc[nt] = __builtin_amdgcn_mfma_f32_16x16x32_bf16(a, bfrag[nt][kc], acc[nt], 0, 0, 0);
    }

    // C/D: col = nt*16 + (lane&15), row = row0 + quad*4 + reg
#pragma unroll
    for (int reg = 0; reg < 4; ++reg) {
        int r = row0 + quad * 4 + reg;
        if (r < NN) {
            float d = rsqrtf(1.0f + (float)cnt[r]);
            if (m == 0) dinv[r] = d;
#pragma unroll
            for (int nt = 0; nt < 8; ++nt)
                Hs[(size_t)r * DIM + nt * 16 + m] = f2fp8(d * acc[nt][reg]);
        }
    }
}

// -------- ELL gather (fp8 in) + fused T-build, 8 lanes/node ----------------
// A2 = bf16(relu(dinv[c]*(Hs[c]+sum Hs[r])+b1)); T[batch[c]][r] += dinv[c]
// per edge (+ self term). uint4 (16 fp8) per lane; 8 rows in flight.
__global__ __launch_bounds__(256) void k_gather_ell(const int* __restrict__ ell,
                                                    const int* __restrict__ deg,
                                                    const int* __restrict__ batch,
                                                    const float* __restrict__ bias,
                                                    const uchar* __restrict__ Hs,
                                                    float* __restrict__ T,
                                                    ushort* __restrict__ out) {
    int gt = blockIdx.x * blockDim.x + threadIdx.x;
    int node = gt >> 3, lane = gt & 7;
    if (node >= NN) return;
    const int* rowp = ell + node * CAP;
    int end = min(deg[node], CAP);
    const float d = rsqrtf(1.0f + (float)end);
    float* Trow = T + (size_t)batch[node] * NNP;
    const size_t off = (size_t)lane * 16;

    float a[16];
#pragma unroll
    for (int j = 0; j < 16; ++j) a[j] = 0.f;
    accfp8x16(a, *(const uint4*)(Hs + (size_t)node * DIM + off));   // self loop
    if (lane == 0) atomicAdd(&Trow[node], d);                       // self T term

    int e = 0;
    for (; e + 8 <= end; e += 8) {
        int r0 = rowp[e], r1 = rowp[e + 1], r2 = rowp[e + 2], r3 = rowp[e + 3];
        int r4 = rowp[e + 4], r5 = rowp[e + 5], r6 = rowp[e + 6], r7 = rowp[e + 7];
        atomicAdd(&Trow[rowp[e + lane]], d);          // all 8 lanes: 1 atomic/edge
        uint4 v0 = *(const uint4*)(Hs + (size_t)r0 * DIM + off);
        uint4 v1 = *(const uint4*)(Hs + (size_t)r1 * DIM + off);
        uint4 v2 = *(const uint4*)(Hs + (size_t)r2 * DIM + off);
        uint4 v3 = *(const uint4*)(Hs + (size_t)r3 * DIM + off);
        uint4 v4 = *(const uint4*)(Hs + (size_t)r4 * DIM + off);
        uint4 v5 = *(const uint4*)(Hs + (size_t)r5 * DIM + off);
        uint4 v6 = *(const uint4*)(Hs + (size_t)r6 * DIM + off);
        uint4 v7 = *(const uint4*)(Hs + (size_t)r7 * DIM + off);
        accfp8x16(a, v0); accfp8x16(a, v1); accfp8x16(a, v2); accfp8x16(a, v3);
        accfp8x16(a, v4); accfp8x16(a, v5); accfp8x16(a, v6); accfp8x16(a, v7);
    }
    for (; e + 4 <= end; e += 4) {
        int r0 = rowp[e], r1 = rowp[e + 1], r2 = rowp[e + 2], r3 = rowp[e + 3];
        if (lane < 4) atomicAdd(&Trow[rowp[e + lane]], d);
        uint4 v0 = *(const uint4*)(Hs + (size_t)r0 * DIM + off);
        uint4 v1 = *(const uint4*)(Hs + (size_t)r1 * DIM + off);
        uint4 v2 = *(const uint4*)(Hs + (size_t)r2 * DIM + off);
        uint4 v3 = *(const uint4*)(Hs + (size_t)r3 * DIM + off);
        accfp8x16(a, v0); accfp8x16(a, v1); accfp8x16(a, v2); accfp8x16(a, v3);
    }
    for (; e < end; ++e) {
        int r = rowp[e];
        if (lane == 0) atomicAdd(&Trow[r], d);
        accfp8x16(a, *(const uint4*)(Hs + (size_t)r * DIM + off));
    }

    uint4 o0, o1;
    {
        const float* bp = bias + off;
#pragma unroll
        for (int j = 0; j < 16; ++j)
            a[j] = fmaxf(fmaf(a[j], d, bp[j]), 0.f);
        o0.x = (unsigned)f2bf(a[0])  | ((unsigned)f2bf(a[1])  << 16);
        o0.y = (unsigned)f2bf(a[2])  | ((unsigned)f2bf(a[3])  << 16);
        o0.z = (unsigned)f2bf(a[4])  | ((unsigned)f2bf(a[5])  << 16);
        o0.w = (unsigned)f2bf(a[6])  | ((unsigned)f2bf(a[7])  << 16);
        o1.x = (unsigned)f2bf(a[8])  | ((unsigned)f2bf(a[9])  << 16);
        o1.y = (unsigned)f2bf(a[10]) | ((unsigned)f2bf(a[11]) << 16);
        o1.z = (unsigned)f2bf(a[12]) | ((unsigned)f2bf(a[13]) << 16);
        o1.w = (unsigned)f2bf(a[14]) | ((unsigned)f2bf(a[15]) << 16);
    }
    ushort* op = out + (size_t)node * DIM + off;
    *(uint4*)op = o0;
    *(uint4*)(op + 8) = o1;
}

// ---------------- pool GEMM: P = (dinv ⊙ T)[64 x NNP] @ A2[NNP x 128] ------
// split-K; all operands streamed sequentially. T zero-padded for k >= NN.
__global__ __launch_bounds__(256) void k_pool_gemm(const float* __restrict__ T,
                                                   const float* __restrict__ dinv,
                                                   const ushort* __restrict__ A2,
                                                   float* __restrict__ partial) {
    const int t = threadIdx.x;
    const int wave = t >> 6, lane = t & 63;
    const int m = lane & 15, quad = lane >> 4;
    const int g = wave * 16 + m;
    const size_t k0 = (size_t)blockIdx.x * KCH;

    float4v acc[8];
#pragma unroll
    for (int nt = 0; nt < 8; ++nt) acc[nt] = (float4v){0.f, 0.f, 0.f, 0.f};

    for (int ks = 0; ks < KCH; ks += 32) {
        const size_t kb = k0 + ks + quad * 8;
        const float* ap = T + (size_t)g * NNP + kb;
        float4 a0 = *(const float4*)ap;
        float4 a1 = *(const float4*)(ap + 4);
        float4 d0 = *(const float4*)(dinv + kb);
        float4 d1 = *(const float4*)(dinv + kb + 4);
        union { short8 v; ushort u[8]; } af;
        af.u[0] = f2bf(a0.x * d0.x); af.u[1] = f2bf(a0.y * d0.y);
        af.u[2] = f2bf(a0.z * d0.z); af.u[3] = f2bf(a0.w * d0.w);
        af.u[4] = f2bf(a1.x * d1.x); af.u[5] = f2bf(a1.y * d1.y);
        af.u[6] = f2bf(a1.z * d1.z); af.u[7] = f2bf(a1.w * d1.w);

        const ushort* bbase = A2 + kb * DIM + m;
#pragma unroll
        for (int nt = 0; nt < 8; ++nt) {
            union { short8 v; ushort u[8]; } bf;
            const ushort* bp = bbase + nt * 16;
#pragma unroll
            for (int j = 0; j < 8; ++j) bf.u[j] = bp[(size_t)j * DIM];
            acc[nt] = __builtin_amdgcn_mfma_f32_16x16x32_bf16(af.v, bf.v, acc[nt], 0, 0, 0);
        }
    }

    float* dst = partial + (size_t)blockIdx.x * (NG * DIM);
#pragma unroll
    for (int reg = 0; reg < 4; ++reg) {
        int gg = wave * 16 + quad * 4 + reg;
#pragma unroll
        for (int nt = 0; nt < 8; ++nt)
            dst[gg * DIM + nt * 16 + m] = acc[nt][reg];
    }
}

// ------- reduce split-K partials -> P[g]; pooled = (P@W2)/cnt + b2; logits -
__global__ __launch_bounds__(128) void k_final(const float* __restrict__ partial,
                                               const float* __restrict__ W2,
                                               const float* __restrict__ b2,
                                               const float* __restrict__ Wlin,
                                               const float* __restrict__ blin,
                                               const int* __restrict__ batch,
                                               float* __restrict__ out) {
    const int g = blockIdx.x;
    const int t = threadIdx.x;
    int start;
    { int a = 0, b = NN; while (a < b) { int m = (a + b) >> 1; if (batch[m] < g) a = m + 1; else b = m; } start = a; }
    int end;
    { int a = 0, b = NN; while (a < b) { int m = (a + b) >> 1; if (batch[m] < g + 1) a = m + 1; else b = m; } end = a; }
    const int cnt = end - start;

    float s = 0.f;
    for (int b = 0; b < KBLK; b += 4) {
        float s0 = partial[(size_t)(b + 0) * (NG * DIM) + g * DIM + t];
        float s1 = partial[(size_t)(b + 1) * (NG * DIM) + g * DIM + t];
        float s2 = partial[(size_t)(b + 2) * (NG * DIM) + g * DIM + t];
        float s3 = partial[(size_t)(b + 3) * (NG * DIM) + g * DIM + t];
        s += (s0 + s1) + (s2 + s3);
    }
    __shared__ float P[DIM];
    P[t] = s;
    __syncthreads();
    float acc = 0.f;
    for (int k = 0; k < DIM; ++k) acc += P[k] * W2[k * DIM + t];   // fp32 W2
    __shared__ float pooled[DIM];
    pooled[t] = (cnt > 0) ? (acc / (float)cnt + b2[t]) : 0.f;
    __syncthreads();
    if (t < NCLS) {
        float s2 = blin[t];
        for (int k = 0; k < DIM; ++k) s2 += pooled[k] * Wlin[k * NCLS + t];
        out[g * NCLS + t] = s2;
    }
}

extern "C" void kernel_launch(void* const* d_in, const int* in_sizes, int n_in,
                              void* d_out, int out_size, void* d_ws, size_t ws_size,
                              hipStream_t stream) {
    const float* x    = (const float*)d_in[0];
    const float* W1   = (const float*)d_in[1];
    const float* b1   = (const float*)d_in[2];
    const float* W2   = (const float*)d_in[3];
    const float* b2   = (const float*)d_in[4];
    const float* Wlin = (const float*)d_in[5];
    const float* blin = (const float*)d_in[6];
    const int* eidx   = (const int*)d_in[7];   // [2, E] flat: rows then cols
    const int* batch  = (const int*)d_in[8];
    float* out = (float*)d_out;

    char* ws = (char*)d_ws;
    int*    cnt   = (int*)(ws + 0);             // NN ints (zeroed; ends as degree)
    float*  dinv  = (float*)(ws + 200000);      // NNP floats (gemm1 writes, tail 0)
    int*    ell   = (int*)(ws + 400704);        // NN*CAP ints = 12.8 MB
    ushort* Wsw   = (ushort*)(ws + 13200704);   // 32768 B (W1 frags)
    float*  T     = (float*)(ws + 13233472);    // 64*NNP fp32 = 12845056 B
    uchar*  Hs1   = (uchar*)(ws + 26078528);    // NN*DIM fp8 = 6.4 MB
    ushort* bufB  = (ushort*)(ws + 32478528);   // NNP*DIM bf16 (A2; tail x T=0)
    float*  poolpt= (float*)(ws + 45323584);    // KBLK*NG*DIM fp32 = 7.3 MB

    const int* erow = eidx;
    const int* ecol = eidx + NE;

    // ---- structure build: zero+Wprep, single-pass ELL fill ----
    k_init<<<SB + 64 + 784 + 1, 256, 0, stream>>>(cnt, W1, Wsw, T, dinv);
    k_fill<<<E4B, 256, 0, stream>>>(erow, ecol, cnt, ell);

    const int gemm_grid = (NN + 63) / 64;            // 782
    const int node_grid = (NN * 8 + 255) / 256;      // 1563

    // layer 1: Hs1 = fp8(dinv*(x @ W1)) (+dinv); A2 = relu(dinv*agg + b1) + T
    k_gemm_mfma<<<gemm_grid, 256, 0, stream>>>(x, Wsw, cnt, Hs1, dinv);
    k_gather_ell<<<node_grid, 256, 0, stream>>>(ell, cnt, batch, b1, Hs1, T, bufB);

    // layer 2 + pool, fully commuted: P = (dinv ⊙ T) @ A2 (streaming split-K)
    k_pool_gemm<<<KBLK, 256, 0, stream>>>(T, dinv, bufB, poolpt);

    // reduce + P@W2 (fp32) + /cnt + b2 + Wlin head
    k_final<<<NG, 128, 0, stream>>>(poolpt, W2, b2, Wlin, blin, batch, out);
}

// Round 14
// 204.319 us; speedup vs baseline: 1.0202x; 1.0202x over previous
//
#include <hip/hip_runtime.h>

#define NN 50000     // nodes
#define NE 600000    // directed edges (self loops handled separately)
#define NG 64        // graphs
#define DIM 128      // feature dim (D == H == 128)
#define NCLS 10
#define SB 196       // ceil(NN/256)
#define NNP 50176    // SB*256 = 224*224 (padded K for pool GEMM)
#define KBLK 224     // split-K blocks for pool GEMM
#define KCH 224      // K-chunk per block (KBLK*KCH == NNP)
#define CAP 64       // ELL row capacity (multinomial max deg ~33; 64 is safe)
#define E2B ((NE / 2 + 255) / 256)   // edge blocks, 2 edges/thread

typedef unsigned short ushort;
typedef unsigned char uchar;
typedef __attribute__((ext_vector_type(8))) short short8;   // 8 bf16 (4 VGPRs)
typedef __attribute__((ext_vector_type(4))) float float4v;  // 4 fp32 acc
typedef __attribute__((ext_vector_type(2))) float float2v;

__device__ __forceinline__ ushort f2bf(float f) {
    unsigned u = __float_as_uint(f);
    u += 0x7fff + ((u >> 16) & 1);          // RNE
    return (ushort)(u >> 16);
}
// fp8 e4m3 (OCP) encode via HW cvt (RNE, satfinite)
__device__ __forceinline__ uchar f2fp8(float f) {
    int p = __builtin_amdgcn_cvt_pk_fp8_f32(f, f, 0, false);
    return (uchar)(p & 0xff);
}
// decode 8 fp8 (uint2) -> accumulate into a[0..7]
__device__ __forceinline__ void accfp8(float* a, uint2 v) {
    float2v p0 = __builtin_amdgcn_cvt_pk_f32_fp8(v.x, false);
    float2v p1 = __builtin_amdgcn_cvt_pk_f32_fp8(v.x, true);
    float2v p2 = __builtin_amdgcn_cvt_pk_f32_fp8(v.y, false);
    float2v p3 = __builtin_amdgcn_cvt_pk_f32_fp8(v.y, true);
    a[0] += p0[0]; a[1] += p0[1]; a[2] += p1[0]; a[3] += p1[1];
    a[4] += p2[0]; a[5] += p2[1]; a[6] += p3[0]; a[7] += p3[1];
}

// ---- init: zero cnt + W1 frag prep + zero T + zero dinv tail --------------
__global__ void k_init(int* __restrict__ cnt, const float* __restrict__ W1,
                       ushort* __restrict__ Wsw, float* __restrict__ T,
                       float* __restrict__ dinv) {
    int b = blockIdx.x, t = threadIdx.x;
    if (b < SB) {
        int i = b * 256 + t;
        if (i < NN) cnt[i] = 0;
    } else if (b < SB + 64) {
        int tid = (b - SB) * 256 + t;     // 16384 entries
        int j = tid & 7;
        int lane = (tid >> 3) & 63;
        int frag = tid >> 9;              // nt*4+kc
        int nt = frag >> 2, kc = frag & 3;
        int k = kc * 32 + (lane >> 4) * 8 + j;
        int n = nt * 16 + (lane & 15);
        Wsw[tid] = f2bf(W1[k * DIM + n]);
    } else if (b < SB + 64 + 784) {
        // zero T: 64*NNP floats = 802816 float4 = 784 blocks * 256 thr * 4
        float4* w4 = (float4*)T;
        int base = (b - SB - 64) * 256 + t;
#pragma unroll
        for (int i = 0; i < 4; ++i)
            w4[base + i * 200704] = make_float4(0.f, 0.f, 0.f, 0.f);
    } else {
        if (t < NNP - NN) dinv[NN + t] = 0.f;   // pad tail (pool_gemm reads it)
    }
}

// ------- single-pass ELL fill by dst (2 edges/thread); cnt ends as degree --
__global__ void k_fill(const int* __restrict__ row, const int* __restrict__ col,
                       int* __restrict__ cnt, int* __restrict__ ell) {
    int e = (blockIdx.x * blockDim.x + threadIdx.x) * 2;
    if (e < NE) {
        int2 r = *(const int2*)(row + e);
        int2 c = *(const int2*)(col + e);
        int p0 = atomicAdd(&cnt[c.x], 1);
        if (p0 < CAP) ell[c.x * CAP + p0] = r.x;
        int p1 = atomicAdd(&cnt[c.y], 1);
        if (p1 < CAP) ell[c.y * CAP + p1] = r.y;
    }
}

// ---------------- MFMA GEMM: Hs[n,c] = fp8(dinv[n] * sum_k x[n,k] W1[k,c]) -
// Also materializes dinv[n] = rsqrt(1+deg[n]) for pool_gemm reuse.
__global__ __launch_bounds__(256) void k_gemm_mfma(const float* __restrict__ Ain,
                                                   const ushort* __restrict__ Wsw,
                                                   const int* __restrict__ cnt,
                                                   uchar* __restrict__ Hs,
                                                   float* __restrict__ dinv) {
    const int t = threadIdx.x;
    const int wave = t >> 6, lane = t & 63;
    const int m = lane & 15, quad = lane >> 4;
    const int row0 = blockIdx.x * 64 + wave * 16;

    short8 bfrag[8][4];
#pragma unroll
    for (int nt = 0; nt < 8; ++nt)
#pragma unroll
        for (int kc = 0; kc < 4; ++kc)
            bfrag[nt][kc] = *(const short8*)(Wsw + ((nt * 4 + kc) * 64 + lane) * 8);

    float4v acc[8];
#pragma unroll
    for (int nt = 0; nt < 8; ++nt) acc[nt] = (float4v){0.f, 0.f, 0.f, 0.f};

    const int row = row0 + m;
    const int rclamp = row < NN ? row : NN - 1;

#pragma unroll
    for (int kc = 0; kc < 4; ++kc) {
        const float* ap = Ain + (size_t)rclamp * DIM + kc * 32 + quad * 8;
        float4 v0 = *(const float4*)ap;
        float4 v1 = *(const float4*)(ap + 4);
        union { short8 v; ushort u[8]; } tmp;
        tmp.u[0] = f2bf(v0.x); tmp.u[1] = f2bf(v0.y);
        tmp.u[2] = f2bf(v0.z); tmp.u[3] = f2bf(v0.w);
        tmp.u[4] = f2bf(v1.x); tmp.u[5] = f2bf(v1.y);
        tmp.u[6] = f2bf(v1.z); tmp.u[7] = f2bf(v1.w);
        short8 a = tmp.v;
#pragma unroll
        for (int nt = 0; nt < 8; ++nt)
            acc[nt] = __builtin_amdgcn_mfma_f32_16x16x32_bf16(a, bfrag[nt][kc], acc[nt], 0, 0, 0);
    }

    // C/D: col = nt*16 + (lane&15), row = row0 + quad*4 + reg
#pragma unroll
    for (int reg = 0; reg < 4; ++reg) {
        int r = row0 + quad * 4 + reg;
        if (r < NN) {
            float d = rsqrtf(1.0f + (float)cnt[r]);
            if (m == 0) dinv[r] = d;
#pragma unroll
            for (int nt = 0; nt < 8; ++nt)
                Hs[(size_t)r * DIM + nt * 16 + m] = f2fp8(d * acc[nt][reg]);
        }
    }
}

// -------- ELL gather (fp8 in) + fused T-build ------------------------------
// A2 = bf16(relu(dinv[c]*(Hs[c]+sum Hs[r])+b1)); T[batch[c]][r] += dinv[c]
// per edge (and T[batch[c]][c] += dinv[c] self term). 16 lanes/node.
__global__ __launch_bounds__(256) void k_gather_ell(const int* __restrict__ ell,
                                                    const int* __restrict__ deg,
                                                    const int* __restrict__ batch,
                                                    const float* __restrict__ bias,
                                                    const uchar* __restrict__ Hs,
                                                    float* __restrict__ T,
                                                    ushort* __restrict__ out) {
    int gt = blockIdx.x * blockDim.x + threadIdx.x;
    int node = gt >> 4, lane = gt & 15;
    if (node >= NN) return;
    const int* rowp = ell + node * CAP;
    int end = min(deg[node], CAP);
    const float d = rsqrtf(1.0f + (float)end);
    float* Trow = T + (size_t)batch[node] * NNP;
    const size_t off = (size_t)lane * 8;

    float a[8] = {0.f, 0.f, 0.f, 0.f, 0.f, 0.f, 0.f, 0.f};
    accfp8(a, *(const uint2*)(Hs + (size_t)node * DIM + off));   // self loop
    if (lane == 0) atomicAdd(&Trow[node], d);                    // self T term

    int e = 0;
    for (; e + 8 <= end; e += 8) {
        int r0 = rowp[e], r1 = rowp[e + 1], r2 = rowp[e + 2], r3 = rowp[e + 3];
        int r4 = rowp[e + 4], r5 = rowp[e + 5], r6 = rowp[e + 6], r7 = rowp[e + 7];
        if (lane < 8) atomicAdd(&Trow[rowp[e + lane]], d);
        uint2 v0 = *(const uint2*)(Hs + (size_t)r0 * DIM + off);
        uint2 v1 = *(const uint2*)(Hs + (size_t)r1 * DIM + off);
        uint2 v2 = *(const uint2*)(Hs + (size_t)r2 * DIM + off);
        uint2 v3 = *(const uint2*)(Hs + (size_t)r3 * DIM + off);
        uint2 v4 = *(const uint2*)(Hs + (size_t)r4 * DIM + off);
        uint2 v5 = *(const uint2*)(Hs + (size_t)r5 * DIM + off);
        uint2 v6 = *(const uint2*)(Hs + (size_t)r6 * DIM + off);
        uint2 v7 = *(const uint2*)(Hs + (size_t)r7 * DIM + off);
        accfp8(a, v0); accfp8(a, v1); accfp8(a, v2); accfp8(a, v3);
        accfp8(a, v4); accfp8(a, v5); accfp8(a, v6); accfp8(a, v7);
    }
    for (; e + 4 <= end; e += 4) {
        int r0 = rowp[e], r1 = rowp[e + 1], r2 = rowp[e + 2], r3 = rowp[e + 3];
        if (lane < 4) atomicAdd(&Trow[rowp[e + lane]], d);
        uint2 v0 = *(const uint2*)(Hs + (size_t)r0 * DIM + off);
        uint2 v1 = *(const uint2*)(Hs + (size_t)r1 * DIM + off);
        uint2 v2 = *(const uint2*)(Hs + (size_t)r2 * DIM + off);
        uint2 v3 = *(const uint2*)(Hs + (size_t)r3 * DIM + off);
        accfp8(a, v0); accfp8(a, v1); accfp8(a, v2); accfp8(a, v3);
    }
    for (; e < end; ++e) {
        int r = rowp[e];
        if (lane == 0) atomicAdd(&Trow[r], d);
        accfp8(a, *(const uint2*)(Hs + (size_t)r * DIM + off));
    }

    float4 b0 = *(const float4*)(bias + off);
    float4 b1 = *(const float4*)(bias + off + 4);
    a[0] = fmaxf(fmaf(a[0], d, b0.x), 0.f); a[1] = fmaxf(fmaf(a[1], d, b0.y), 0.f);
    a[2] = fmaxf(fmaf(a[2], d, b0.z), 0.f); a[3] = fmaxf(fmaf(a[3], d, b0.w), 0.f);
    a[4] = fmaxf(fmaf(a[4], d, b1.x), 0.f); a[5] = fmaxf(fmaf(a[5], d, b1.y), 0.f);
    a[6] = fmaxf(fmaf(a[6], d, b1.z), 0.f); a[7] = fmaxf(fmaf(a[7], d, b1.w), 0.f);
    uint4 o;
    o.x = (unsigned)f2bf(a[0]) | ((unsigned)f2bf(a[1]) << 16);
    o.y = (unsigned)f2bf(a[2]) | ((unsigned)f2bf(a[3]) << 16);
    o.z = (unsigned)f2bf(a[4]) | ((unsigned)f2bf(a[5]) << 16);
    o.w = (unsigned)f2bf(a[6]) | ((unsigned)f2bf(a[7]) << 16);
    *(uint4*)(out + (size_t)node * DIM + off) = o;
}

// ---------------- pool GEMM: P = (dinv ⊙ T)[64 x NNP] @ A2[NNP x 128] ------
// split-K; all operands streamed sequentially. T zero-padded for k >= NN.
__global__ __launch_bounds__(256) void k_pool_gemm(const float* __restrict__ T,
                                                   const float* __restrict__ dinv,
                                                   const ushort* __restrict__ A2,
                                                   float* __restrict__ partial) {
    const int t = threadIdx.x;
    const int wave = t >> 6, lane = t & 63;
    const int m = lane & 15, quad = lane >> 4;
    const int g = wave * 16 + m;
    const size_t k0 = (size_t)blockIdx.x * KCH;

    float4v acc[8];
#pragma unroll
    for (int nt = 0; nt < 8; ++nt) acc[nt] = (float4v){0.f, 0.f, 0.f, 0.f};

    for (int ks = 0; ks < KCH; ks += 32) {
        const size_t kb = k0 + ks + quad * 8;
        const float* ap = T + (size_t)g * NNP + kb;
        float4 a0 = *(const float4*)ap;
        float4 a1 = *(const float4*)(ap + 4);
        float4 d0 = *(const float4*)(dinv + kb);
        float4 d1 = *(const float4*)(dinv + kb + 4);
        union { short8 v; ushort u[8]; } af;
        af.u[0] = f2bf(a0.x * d0.x); af.u[1] = f2bf(a0.y * d0.y);
        af.u[2] = f2bf(a0.z * d0.z); af.u[3] = f2bf(a0.w * d0.w);
        af.u[4] = f2bf(a1.x * d1.x); af.u[5] = f2bf(a1.y * d1.y);
        af.u[6] = f2bf(a1.z * d1.z); af.u[7] = f2bf(a1.w * d1.w);

        const ushort* bbase = A2 + kb * DIM + m;
#pragma unroll
        for (int nt = 0; nt < 8; ++nt) {
            union { short8 v; ushort u[8]; } bf;
            const ushort* bp = bbase + nt * 16;
#pragma unroll
            for (int j = 0; j < 8; ++j) bf.u[j] = bp[(size_t)j * DIM];
            acc[nt] = __builtin_amdgcn_mfma_f32_16x16x32_bf16(af.v, bf.v, acc[nt], 0, 0, 0);
        }
    }

    float* dst = partial + (size_t)blockIdx.x * (NG * DIM);
#pragma unroll
    for (int reg = 0; reg < 4; ++reg) {
        int gg = wave * 16 + quad * 4 + reg;
#pragma unroll
        for (int nt = 0; nt < 8; ++nt)
            dst[gg * DIM + nt * 16 + m] = acc[nt][reg];
    }
}

// ------- reduce split-K partials -> P[g]; pooled = (P@W2)/cnt + b2; logits -
__global__ __launch_bounds__(128) void k_final(const float* __restrict__ partial,
                                               const float* __restrict__ W2,
                                               const float* __restrict__ b2,
                                               const float* __restrict__ Wlin,
                                               const float* __restrict__ blin,
                                               const int* __restrict__ batch,
                                               float* __restrict__ out) {
    const int g = blockIdx.x;
    const int t = threadIdx.x;
    int start;
    { int a = 0, b = NN; while (a < b) { int m = (a + b) >> 1; if (batch[m] < g) a = m + 1; else b = m; } start = a; }
    int end;
    { int a = 0, b = NN; while (a < b) { int m = (a + b) >> 1; if (batch[m] < g + 1) a = m + 1; else b = m; } end = a; }
    const int cnt = end - start;

    float s = 0.f;
    for (int b = 0; b < KBLK; b += 4) {
        float s0 = partial[(size_t)(b + 0) * (NG * DIM) + g * DIM + t];
        float s1 = partial[(size_t)(b + 1) * (NG * DIM) + g * DIM + t];
        float s2 = partial[(size_t)(b + 2) * (NG * DIM) + g * DIM + t];
        float s3 = partial[(size_t)(b + 3) * (NG * DIM) + g * DIM + t];
        s += (s0 + s1) + (s2 + s3);
    }
    __shared__ float P[DIM];
    P[t] = s;
    __syncthreads();
    float acc = 0.f;
    for (int k = 0; k < DIM; ++k) acc += P[k] * W2[k * DIM + t];   // fp32 W2
    __shared__ float pooled[DIM];
    pooled[t] = (cnt > 0) ? (acc / (float)cnt + b2[t]) : 0.f;
    __syncthreads();
    if (t < NCLS) {
        float s2 = blin[t];
        for (int k = 0; k < DIM; ++k) s2 += pooled[k] * Wlin[k * NCLS + t];
        out[g * NCLS + t] = s2;
    }
}

extern "C" void kernel_launch(void* const* d_in, const int* in_sizes, int n_in,
                              void* d_out, int out_size, void* d_ws, size_t ws_size,
                              hipStream_t stream) {
    const float* x    = (const float*)d_in[0];
    const float* W1   = (const float*)d_in[1];
    const float* b1   = (const float*)d_in[2];
    const float* W2   = (const float*)d_in[3];
    const float* b2   = (const float*)d_in[4];
    const float* Wlin = (const float*)d_in[5];
    const float* blin = (const float*)d_in[6];
    const int* eidx   = (const int*)d_in[7];   // [2, E] flat: rows then cols
    const int* batch  = (const int*)d_in[8];
    float* out = (float*)d_out;

    char* ws = (char*)d_ws;
    int*    cnt   = (int*)(ws + 0);             // NN ints (zeroed; ends as degree)
    float*  dinv  = (float*)(ws + 200000);      // NNP floats (gemm1 writes, tail 0)
    int*    ell   = (int*)(ws + 400704);        // NN*CAP ints = 12.8 MB
    ushort* Wsw   = (ushort*)(ws + 13200704);   // 32768 B (W1 frags)
    float*  T     = (float*)(ws + 13233472);    // 64*NNP fp32 = 12845056 B
    uchar*  Hs1   = (uchar*)(ws + 26078528);    // NN*DIM fp8 = 6.4 MB
    ushort* bufB  = (ushort*)(ws + 32478528);   // NNP*DIM bf16 (A2; tail x T=0)
    float*  poolpt= (float*)(ws + 45323584);    // KBLK*NG*DIM fp32 = 7.3 MB

    const int* erow = eidx;
    const int* ecol = eidx + NE;

    // ---- structure build: zero+Wprep, single-pass ELL fill ----
    k_init<<<SB + 64 + 784 + 1, 256, 0, stream>>>(cnt, W1, Wsw, T, dinv);
    k_fill<<<E2B, 256, 0, stream>>>(erow, ecol, cnt, ell);

    const int gemm_grid = (NN + 63) / 64;            // 782
    const int node_grid = (NN * 16 + 255) / 256;     // 3125

    // layer 1: Hs1 = fp8(dinv*(x @ W1)) (+dinv); A2 = relu(dinv*agg + b1) + T
    k_gemm_mfma<<<gemm_grid, 256, 0, stream>>>(x, Wsw, cnt, Hs1, dinv);
    k_gather_ell<<<node_grid, 256, 0, stream>>>(ell, cnt, batch, b1, Hs1, T, bufB);

    // layer 2 + pool, fully commuted: P = (dinv ⊙ T) @ A2 (streaming split-K)
    k_pool_gemm<<<KBLK, 256, 0, stream>>>(T, dinv, bufB, poolpt);

    // reduce + P@W2 (fp32) + /cnt + b2 + Wlin head
    k_final<<<NG, 128, 0, stream>>>(poolpt, W2, b2, Wlin, blin, batch, out);
}